// Round 3
// baseline (221.339 us; speedup 1.0000x reference)
//
#include <hip/hip_runtime.h>

#define NN 4096
#define CCH 128

typedef float f2 __attribute__((ext_vector_type(2)));
typedef float f4 __attribute__((ext_vector_type(4)));

__device__ __forceinline__ void cmpex(float& x, float& y) {
  float mn = fminf(x, y);
  y = fmaxf(x, y);
  x = mn;
}

template <int N>
__device__ __forceinline__ void bitonic_merge(float* s) {
#pragma unroll
  for (int jm = N / 2; jm > 0; jm >>= 1)
#pragma unroll
    for (int i = 0; i < N; ++i)
      if ((i & jm) == 0) cmpex(s[i], s[i + jm]);
}

// merge two sorted-4 (asc) lists, keep lowest 4 sorted asc in a[]
__device__ __forceinline__ void merge44(float* a, const float* b) {
  float m0 = fminf(a[0], b[3]), m1 = fminf(a[1], b[2]);
  float m2 = fminf(a[2], b[1]), m3 = fminf(a[3], b[0]);
  cmpex(m0, m2); cmpex(m1, m3); cmpex(m0, m1); cmpex(m2, m3);
  a[0] = m0; a[1] = m1; a[2] = m2; a[3] = m3;
}

__device__ __forceinline__ unsigned long long mk_key(float d, int idx) {
  unsigned int f = __float_as_uint(d);
  f ^= (f >> 31) ? 0xFFFFFFFFu : 0x80000000u;
  return ((unsigned long long)f << 32) | (unsigned int)idx;
}

// ---------------------------------------------------------------- kernel 0: weight packing + pts4 + packed-pair SoA
__global__ __launch_bounds__(256) void transpose_w(
    const float* __restrict__ wq, const float* __restrict__ wk, const float* __restrict__ wv,
    const float* __restrict__ w1, const float* __restrict__ xyz,
    float* __restrict__ wTq, float* __restrict__ wTk, float* __restrict__ wTv,
    float* __restrict__ w1T, float* __restrict__ wPack, float4* __restrict__ pts4,
    float* __restrict__ pp) {
  int t = blockIdx.x * 256 + threadIdx.x;
  if (t < 64 * 262) {
    int o = t / 262, c = t - o * 262;
    wTq[c * 64 + o] = wq[t];
    wTk[c * 64 + o] = wk[t];
    wTv[c * 64 + o] = wv[t];
  }
  if (t < 128 * 64) {
    int r = t >> 6, c2 = t & 63;
    w1T[c2 * 128 + r] = w1[t];  // w1T[o][c]
  }
  if (t < 49152) {  // wPack float4-layout [half][ct16][mm3][ph2][o64] = {U_{2ph},T_{2ph},U_{2ph+1},T_{2ph+1}}
    int c  = t & 3;
    int o  = (t >> 2) & 63;
    int ph = (t >> 8) & 1;
    int t2 = t >> 9;         // (half*16+ct)*3 + mm
    int mm = t2 % 3;
    int t3 = t2 / 3;         // half*16+ct
    int ct = t3 & 15;
    int half = t3 >> 4;
    const float* wsrc = (mm == 0) ? wq : ((mm == 1) ? wk : wv);
    int isT = c & 1;
    int rr  = 2 * ph + (c >> 1);
    int col = (isT ? 134 : 6) + 4 * (half * 16 + ct) + rr;
    wPack[t] = wsrc[o * 262 + col];
  }
  if (t < 4 * NN) {  // pts4[b*4096+i] = (x,y,z,|x|^2); pp = pair-interleaved SoA
    int bb = t >> 12, i = t & 4095;
    const float* xb = xyz + (size_t)bb * 3 * NN;
    float x = xb[i], y = xb[NN + i], z = xb[2 * NN + i];
    float w = x * x + y * y + z * z;
    pts4[t] = make_float4(x, y, z, w);
    float* pb = pp + ((size_t)bb * 2048 + (i >> 1)) * 8 + (i & 1);
    pb[0] = x; pb[2] = y; pb[4] = z; pb[6] = w;
  }
}

// ---------------------------------------------------------------- kernel 1: kNN halves
// packed-fp32 distance; first half-window distances cached in registers (no pass-2
// reload/recompute); single atomic per candidate pair in the hit path.
__global__ __launch_bounds__(1024, 4) void knn_half(const float4* __restrict__ pts4,
                                                    const float* __restrict__ pp,
                                                    unsigned long long* __restrict__ keys_ws) {
  __shared__ float bufA[64 * 64];
  __shared__ float bufB[64 * 64];
  __shared__ unsigned long long hits[32 * 65];
  __shared__ int cnt[64];
  const int b  = blockIdx.x >> 7;
  const int g  = (blockIdx.x >> 1) & 63;
  const int h  = blockIdx.x & 1;
  const int n0 = g << 6;
  const int ql = threadIdx.x & 63;
  const int ch = __builtin_amdgcn_readfirstlane(threadIdx.x >> 6);
  if (threadIdx.x < 64) cnt[threadIdx.x] = 0;
  const int q = n0 + ql;
  const float4* pb4 = pts4 + ((size_t)b << 12);
  const float4 me = pb4[q];
  const f2 mex = {me.x, me.x}, mey = {me.y, me.y}, mez = {me.z, me.z}, mew = {me.w, me.w};
  const f2 mneg2 = {-2.0f, -2.0f};
  const float* ppb = pp + ((size_t)b << 14);  // b * 2048 pairs * 8 floats
  const int m0 = (h << 11) + (ch << 7);
  // exactly one wave's 128-window contains this block's 64 queries:
  const bool ovl = (((h << 4) + ch) == (n0 >> 7));
  // ---- pass 1: top-4 per 128-candidate window, caching first-half distances ----
  f2 dc[32];  // statically-indexed under full unroll -> registers
  float t0[4], t1[4], t2[4], t3[4];
#pragma unroll
  for (int u = 0; u < 4; ++u) { t0[u] = 3.0e38f; t1[u] = 3.0e38f; t2[u] = 3.0e38f; t3[u] = 3.0e38f; }
#pragma unroll
  for (int it = 0; it < 16; ++it) {
    const int mb = m0 + it * 8;
    const f4* pg4 = reinterpret_cast<const f4*>(ppb + (size_t)mb * 4);
    f2 d2[4];
#pragma unroll
    for (int u = 0; u < 4; ++u) {
      f4 A = pg4[2 * u], B = pg4[2 * u + 1];
      f2 X = A.xy, Y = A.zw, Z = B.xy, W = B.zw;
      f2 dot = X * mex + Y * mey + Z * mez;
      d2[u] = dot * mneg2 + (W + mew);
    }
    if (ovl) {  // mask self-distance; cached copies inherit the exclusion
#pragma unroll
      for (int u = 0; u < 4; ++u) {
        d2[u].x = (mb + 2 * u     == q) ? 3.0e38f : d2[u].x;
        d2[u].y = (mb + 2 * u + 1 == q) ? 3.0e38f : d2[u].y;
      }
    }
    if (it < 8) {
#pragma unroll
      for (int u = 0; u < 4; ++u) dc[it * 4 + u] = d2[u];
    }
#pragma unroll
    for (int u = 0; u < 4; ++u) {
      float* bd = (u == 0) ? t0 : (u == 1) ? t1 : (u == 2) ? t2 : t3;
      float dx = d2[u].x, dy = d2[u].y;
      bd[3] = __builtin_amdgcn_fmed3f(dx, bd[2], bd[3]);
      bd[2] = __builtin_amdgcn_fmed3f(dx, bd[1], bd[2]);
      bd[1] = __builtin_amdgcn_fmed3f(dx, bd[0], bd[1]);
      bd[0] = fminf(bd[0], dx);
      bd[3] = __builtin_amdgcn_fmed3f(dy, bd[2], bd[3]);
      bd[2] = __builtin_amdgcn_fmed3f(dy, bd[1], bd[2]);
      bd[1] = __builtin_amdgcn_fmed3f(dy, bd[0], bd[1]);
      bd[0] = fminf(bd[0], dy);
    }
  }
  // in-register merge of the 4 sorted-4 lists -> lowest-4 of the 128 window
  merge44(t0, t1); merge44(t2, t3); merge44(t0, t2);
  {
    const int r0 = (ch * 4) * 64 + ql;
    bufA[r0] = t0[0]; bufA[r0 + 64] = t0[1]; bufA[r0 + 128] = t0[2]; bufA[r0 + 192] = t0[3];
  }
  __syncthreads();
  // ---- tau merge tree: fixed-address bitonic networks ----
  if (ch < 8) {  // 8 merges of (4,4)->8
    const int base = 8 * ch;
    float s[8];
#pragma unroll
    for (int i = 0; i < 4; ++i) s[i] = bufA[(base + i) * 64 + ql];
#pragma unroll
    for (int i = 0; i < 4; ++i) s[4 + i] = bufA[(base + 7 - i) * 64 + ql];  // B reversed
    bitonic_merge<8>(s);
#pragma unroll
    for (int i = 0; i < 8; ++i) bufB[(base + i) * 64 + ql] = s[i];
  }
  __syncthreads();
  if (ch < 4) {  // 4 merges of (8,8)->16
    const int base = 16 * ch;
    float s[16];
#pragma unroll
    for (int i = 0; i < 8; ++i) s[i] = bufB[(base + i) * 64 + ql];
#pragma unroll
    for (int i = 0; i < 8; ++i) s[8 + i] = bufB[(base + 15 - i) * 64 + ql];
    bitonic_merge<16>(s);
#pragma unroll
    for (int i = 0; i < 16; ++i) bufA[(base + i) * 64 + ql] = s[i];
  }
  __syncthreads();
  if (ch < 2) {  // 2 merges of (16,16)->lowest-16 sorted
    const int base = 32 * ch;
    float l[16];
#pragma unroll
    for (int i = 0; i < 16; ++i)
      l[i] = fminf(bufA[(base + i) * 64 + ql], bufA[(base + 31 - i) * 64 + ql]);
    bitonic_merge<16>(l);
#pragma unroll
    for (int i = 0; i < 16; ++i) bufB[(16 * ch + i) * 64 + ql] = l[i];
  }
  __syncthreads();
  if (ch == 0) {  // final: tau = 16th smallest = max of pairwise lows
    float m[16];
#pragma unroll
    for (int i = 0; i < 16; ++i)
      m[i] = fminf(bufB[i * 64 + ql], bufB[(31 - i) * 64 + ql]);
    float t = m[0];
#pragma unroll
    for (int i = 1; i < 16; ++i) t = fmaxf(t, m[i]);
    bufA[15 * 64 + ql] = t;
  }
  __syncthreads();
  const float tau = bufA[15 * 64 + ql];
  // ---- pass 2a: cached half — no loads, no distance recompute ----
#pragma unroll
  for (int pi = 0; pi < 32; ++pi) {
    const f2 d = dc[pi];
    const int i0 = m0 + 2 * pi;
    const bool hx = d.x <= tau, hy = d.y <= tau;
    if (hx || hy) {
      const int nh = (int)hx + (int)hy;
      int pos = atomicAdd(&cnt[ql], nh);
      unsigned long long kx = mk_key(d.x, i0), ky = mk_key(d.y, i0 + 1);
      if (pos < 32) hits[pos * 65 + ql] = hx ? kx : ky;
      if (nh == 2 && pos < 31) hits[(pos + 1) * 65 + ql] = ky;
    }
  }
  // ---- pass 2b: second half — recompute (self-mask only if queries live here) ----
  const bool ovl2 = ovl && ((n0 & 64) != 0);
#pragma unroll
  for (int it = 8; it < 16; ++it) {
    const int mb = m0 + it * 8;
    const f4* pg4 = reinterpret_cast<const f4*>(ppb + (size_t)mb * 4);
#pragma unroll
    for (int u = 0; u < 4; ++u) {
      f4 A = pg4[2 * u], B = pg4[2 * u + 1];
      f2 X = A.xy, Y = A.zw, Z = B.xy, W = B.zw;
      f2 dot = X * mex + Y * mey + Z * mez;
      f2 d = dot * mneg2 + (W + mew);
      if (ovl2) {
        d.x = (mb + 2 * u     == q) ? 3.0e38f : d.x;
        d.y = (mb + 2 * u + 1 == q) ? 3.0e38f : d.y;
      }
      const int i0 = mb + 2 * u;
      const bool hx = d.x <= tau, hy = d.y <= tau;
      if (hx || hy) {
        const int nh = (int)hx + (int)hy;
        int pos = atomicAdd(&cnt[ql], nh);
        unsigned long long kx = mk_key(d.x, i0), ky = mk_key(d.y, i0 + 1);
        if (pos < 32) hits[pos * 65 + ql] = hx ? kx : ky;
        if (nh == 2 && pos < 31) hits[(pos + 1) * 65 + ql] = ky;
      }
    }
  }
  __syncthreads();
  const int l5 = threadIdx.x & 31;
#pragma unroll
  for (int t = 0; t < 2; ++t) {
    const int qq = (t * 1024 + (int)threadIdx.x) >> 5;
    int nv = cnt[qq]; nv = nv > 32 ? 32 : nv;
    unsigned long long key = (l5 < nv) ? hits[l5 * 65 + qq] : ~0ULL;
#pragma unroll
    for (int k = 2; k <= 32; k <<= 1) {
#pragma unroll
      for (int jm = k >> 1; jm > 0; jm >>= 1) {
        unsigned long long o2 = __shfl_xor(key, jm, 32);
        bool asc = ((l5 & k) == 0);
        bool lower = ((l5 & jm) == 0);
        unsigned long long mn = key < o2 ? key : o2;
        unsigned long long mx = key < o2 ? o2 : key;
        key = (lower == asc) ? mn : mx;
      }
    }
    if (l5 < 16) {
      const size_t gq = (size_t)((b << 12) + n0 + qq);
      keys_ws[((size_t)h << 18) + gq * 16 + l5] = key;
    }
  }
}

// ---------------------------------------------------------------- kernel 2: projections (packed U/T accumulators)
__global__ __launch_bounds__(512) void proj_kernel(
    const float* __restrict__ feature, const float* __restrict__ xyz,
    const float* __restrict__ wTq, const float* __restrict__ wTk, const float* __restrict__ wTv,
    const float* __restrict__ wPack,
    const float* __restrict__ bq, const float* __restrict__ bk, const float* __restrict__ bv,
    float* __restrict__ uqA, float* __restrict__ cq,
    float2* __restrict__ ukv,
    float* __restrict__ ck, float* __restrict__ cv) {
  __shared__ float fl[64][132];        // 33.8 KB
  __shared__ float4 wl[16 * 3 * 2 * 64];   // 96 KB
  const int p0 = blockIdx.x << 6;
  const int b  = p0 >> 12;
  const int n0 = p0 & 4095;
  {
    const int i  = threadIdx.x & 63;
    const int c0 = threadIdx.x >> 6;
    const float* fb = feature + (size_t)b * CCH * NN + n0 + i;
    for (int cc = c0; cc < CCH; cc += 8) fl[i][cc] = fb[(size_t)cc * NN];
    if (threadIdx.x < 192) {
      const int d = threadIdx.x >> 6;
      fl[i][128 + d] = xyz[((size_t)b * 3 + d) * NN + n0 + i];
    }
  }
  const int o  = threadIdx.x & 63;
  const int pg = threadIdx.x >> 6;
  const float4* wp = reinterpret_cast<const float4*>(wPack);
  f2 acc[3][8];
#pragma unroll
  for (int mm = 0; mm < 3; ++mm)
#pragma unroll
    for (int s = 0; s < 8; ++s) acc[mm][s] = (f2){0.f, 0.f};

  for (int half = 0; half < 2; ++half) {
    __syncthreads();
    for (int d4 = threadIdx.x; d4 < 6144; d4 += 512)
      wl[d4] = wp[half * 6144 + d4];
    __syncthreads();
#pragma unroll 4
    for (int ct = 0; ct < 16; ++ct) {
      float4 wA[3], wB[3];
#pragma unroll
      for (int mm = 0; mm < 3; ++mm) {
        wA[mm] = wl[((ct * 3 + mm) * 2 + 0) * 64 + o];
        wB[mm] = wl[((ct * 3 + mm) * 2 + 1) * 64 + o];
      }
      const int cglob = half * 16 + ct;
#pragma unroll
      for (int s = 0; s < 8; ++s) {
        const float4 f4w = *reinterpret_cast<const float4*>(&fl[pg * 8 + s][4 * cglob]);
        const f2 sx = {f4w.x, f4w.x}, sy = {f4w.y, f4w.y}, sz = {f4w.z, f4w.z}, sw = {f4w.w, f4w.w};
#pragma unroll
        for (int mm = 0; mm < 3; ++mm) {
          const f2* a2 = reinterpret_cast<const f2*>(&wA[mm]);
          const f2* b2 = reinterpret_cast<const f2*>(&wB[mm]);
          f2 a = acc[mm][s];
          a += sx * a2[0];   // {U,T} += f.x * {U0,T0}
          a += sy * a2[1];
          a += sz * b2[0];
          a += sw * b2[1];
          acc[mm][s] = a;
        }
      }
    }
  }
  float wxu[3][3], wxt[3][3];
#pragma unroll
  for (int dd = 0; dd < 3; ++dd) {
    wxu[0][dd] = wTq[dd * 64 + o]; wxt[0][dd] = wTq[(3 + dd) * 64 + o];
    wxu[1][dd] = wTk[dd * 64 + o]; wxt[1][dd] = wTk[(3 + dd) * 64 + o];
    wxu[2][dd] = wTv[dd * 64 + o]; wxt[2][dd] = wTv[(3 + dd) * 64 + o];
  }
  const float bo0 = bq[o], bo1 = bk[o], bo2 = bv[o];
#pragma unroll
  for (int s = 0; s < 8; ++s) {
    const int p = pg * 8 + s;
    const float x = fl[p][128], y = fl[p][129], z = fl[p][130];
    const size_t gp = ((size_t)(p0 + p)) * 64 + o;
    float uu, tt;
    uu = acc[0][s].x + wxu[0][0] * x + wxu[0][1] * y + wxu[0][2] * z;
    tt = acc[0][s].y + wxt[0][0] * x + wxt[0][1] * y + wxt[0][2] * z;
    uqA[gp] = uu; cq[gp] = tt + bo0 - uu;
    const float uk_ = acc[1][s].x + wxu[1][0] * x + wxu[1][1] * y + wxu[1][2] * z;
    tt = acc[1][s].y + wxt[1][0] * x + wxt[1][1] * y + wxt[1][2] * z;
    ck[gp] = tt + bo1 - uk_;
    const float uv_ = acc[2][s].x + wxu[2][0] * x + wxu[2][1] * y + wxu[2][2] * z;
    tt = acc[2][s].y + wxt[2][0] * x + wxt[2][1] * y + wxt[2][2] * z;
    cv[gp] = tt + bo2 - uv_;
    ukv[gp] = make_float2(uk_, uv_);
  }
}

// ---------------------------------------------------------------- kernel 3: attention core + inline half-merge
__global__ __launch_bounds__(256) void attn_core(
    const unsigned long long* __restrict__ keys_ws,
    const float* __restrict__ uqA, const float* __restrict__ cq,
    const float2* __restrict__ ukv,
    const float* __restrict__ ck, const float* __restrict__ cv,
    float* __restrict__ res_ws) {
  __shared__ float kq[4][24][68];
  const int slot = threadIdx.x >> 6;
  const int o    = threadIdx.x & 63;
  const int p = (blockIdx.x << 2) + slot;
  const int b = p >> 12;
  const int l5 = o & 31;
  unsigned long long key =
      (l5 < 16) ? keys_ws[(size_t)p * 16 + l5]
                : keys_ws[((size_t)1 << 18) + (size_t)p * 16 + (31 - l5)];  // B reversed
#pragma unroll
  for (int jm = 16; jm > 0; jm >>= 1) {
    unsigned long long o2 = __shfl_xor(key, jm, 32);
    bool lower = ((l5 & jm) == 0);
    unsigned long long mn = key < o2 ? key : o2;
    unsigned long long mx = key < o2 ? o2 : key;
    key = lower ? mn : mx;
  }
  const int kidx = (int)(key & 0xFFFFFFFFu);
  const size_t pb = (size_t)p * 64 + o;
  const float cqo = cq[pb], cko = ck[pb], cvo = cv[pb];
  const int rowbase = (b << 12) * 64;
  float v[16];
#pragma unroll
  for (int j = 0; j < 16; ++j) {
    int nb = __shfl(kidx, j);
    int row = rowbase + nb * 64 + o;
    float2 kv = ukv[row];
    kq[slot][j][o] = kv.x + cko;
    v[j] = kv.y + cvo;
    if (j < 8) kq[slot][16 + j][o] = uqA[row] + cqo;
  }
  const int i  = o >> 3;
  const int jj = o & 7;
  const float* qrow = &kq[slot][16 + i][0];
  const float* k0r  = &kq[slot][jj][0];
  const float* k1r  = &kq[slot][8 + jj][0];
  float s0 = 0.f, s1 = 0.f;
#pragma unroll
  for (int t = 0; t < 16; ++t) {
    float4 q4 = *reinterpret_cast<const float4*>(qrow + 4 * t);
    float4 a4 = *reinterpret_cast<const float4*>(k0r + 4 * t);
    float4 c4 = *reinterpret_cast<const float4*>(k1r + 4 * t);
    s0 += q4.x * a4.x + q4.y * a4.y + q4.z * a4.z + q4.w * a4.w;
    s1 += q4.x * c4.x + q4.y * c4.y + q4.z * c4.z + q4.w * c4.w;
  }
  float mx = fmaxf(s0, s1);
  mx = fmaxf(mx, __shfl_xor(mx, 1));
  mx = fmaxf(mx, __shfl_xor(mx, 2));
  mx = fmaxf(mx, __shfl_xor(mx, 4));
  float e0 = __expf(s0 - mx), e1 = __expf(s1 - mx);
  float den = e0 + e1;
  den += __shfl_xor(den, 1);
  den += __shfl_xor(den, 2);
  den += __shfl_xor(den, 4);
  const float inv = 1.0f / den;
  float w0 = e0 * inv, w1s = e1 * inv;
  w0 += __shfl_xor(w0, 8);   w1s += __shfl_xor(w1s, 8);
  w0 += __shfl_xor(w0, 16);  w1s += __shfl_xor(w1s, 16);
  w0 += __shfl_xor(w0, 32);  w1s += __shfl_xor(w1s, 32);
  float res = 0.f;
#pragma unroll
  for (int j = 0; j < 8; ++j) {
    res += __shfl(w0, j)  * v[j];
    res += __shfl(w1s, j) * v[j + 8];
  }
  res_ws[pb] = res;
}

// ---------------------------------------------------------------- kernel 4: output epilogue
__global__ __launch_bounds__(512) void out_kernel(
    const float* __restrict__ feature, const float* __restrict__ res,
    const float* __restrict__ w1T, const float* __restrict__ b1,
    float* __restrict__ out) {
  __shared__ float rT[64][66];
  const int p0 = blockIdx.x << 6;
  const int b  = p0 >> 12;
  const int n0 = p0 & 4095;
  {
    const int o = threadIdx.x & 63;
    for (int pp = threadIdx.x >> 6; pp < 64; pp += 8)
      rT[o][pp] = res[(size_t)(p0 + pp) * 64 + o];
  }
  __syncthreads();
  const int n = threadIdx.x & 63;
  const int c0 = (threadIdx.x >> 6) * 16;
  float acc[16];
#pragma unroll
  for (int cc = 0; cc < 16; ++cc) acc[cc] = b1[c0 + cc];
  for (int o = 0; o < 64; ++o) {
    const float rr = rT[o][n];
    const float* wrow = &w1T[o * 128 + c0];
#pragma unroll
    for (int cc = 0; cc < 16; ++cc) acc[cc] += wrow[cc] * rr;
  }
#pragma unroll
  for (int cc = 0; cc < 16; ++cc) {
    const size_t gi = ((size_t)(b * 128 + c0 + cc) << 12) + n0 + n;
    out[gi] = acc[cc] + feature[gi];
  }
}

// ---------------------------------------------------------------- launch
extern "C" void kernel_launch(void* const* d_in, const int* in_sizes, int n_in,
                              void* d_out, int out_size, void* d_ws, size_t ws_size,
                              hipStream_t stream) {
  const float* feature = (const float*)d_in[0];
  const float* xyz     = (const float*)d_in[1];
  const float* wq      = (const float*)d_in[2];
  const float* bq      = (const float*)d_in[3];
  const float* wk      = (const float*)d_in[4];
  const float* bk      = (const float*)d_in[5];
  const float* wv      = (const float*)d_in[6];
  const float* bv      = (const float*)d_in[7];
  const float* w1      = (const float*)d_in[8];
  const float* b1      = (const float*)d_in[9];
  float* out = (float*)d_out;

  char* ws = (char*)d_ws;
  float4* pts4 = (float4*)(ws + (1u << 20));        // 256 KB
  float*  pp   = (float*)(ws + (1u << 20) + 262144); // 256 KB packed-pair SoA
  float*  uqA  = (float*)(ws + (2u << 20));         // 4 MB
  float*  cq   = (float*)(ws + (6u << 20));         // 4 MB
  float*  ck   = (float*)(ws + (10u << 20));        // 4 MB
  float*  cv   = (float*)(ws + (14u << 20));        // 4 MB
  float2* ukv  = (float2*)(ws + (18u << 20));       // 8 MB
  float*  res  = (float*)(ws + (26u << 20));        // 4 MB
  float*  wTq  = (float*)(ws + (30u << 20));
  float*  wTk  = wTq + 262 * 64;
  float*  wTv  = wTk + 262 * 64;
  float*  w1T  = wTv + 262 * 64;
  float*  wPk  = w1T + 128 * 64;                    // 49152 floats
  unsigned long long* keys = (unsigned long long*)(ws + (31u << 20));  // 4 MB

  transpose_w<<<192, 256, 0, stream>>>(wq, wk, wv, w1, xyz, wTq, wTk, wTv, w1T, wPk, pts4, pp);
  knn_half<<<512, 1024, 0, stream>>>(pts4, pp, keys);
  proj_kernel<<<256, 512, 0, stream>>>(feature, xyz, wTq, wTk, wTv, wPk, bq, bk, bv,
                                       uqA, cq, ukv, ck, cv);
  attn_core<<<4096, 256, 0, stream>>>(keys, uqA, cq, ukv, ck, cv, res);
  out_kernel<<<256, 512, 0, stream>>>(feature, res, w1T, b1, out);
}

// Round 4
// 196.819 us; speedup vs baseline: 1.1246x; 1.1246x over previous
//
#include <hip/hip_runtime.h>

#define NN 4096
#define CCH 128

typedef float f2 __attribute__((ext_vector_type(2)));
typedef float f4 __attribute__((ext_vector_type(4)));

__device__ __forceinline__ void cmpex(float& x, float& y) {
  float mn = fminf(x, y);
  y = fmaxf(x, y);
  x = mn;
}

template <int N>
__device__ __forceinline__ void bitonic_merge(float* s) {
#pragma unroll
  for (int jm = N / 2; jm > 0; jm >>= 1)
#pragma unroll
    for (int i = 0; i < N; ++i)
      if ((i & jm) == 0) cmpex(s[i], s[i + jm]);
}

// merge two sorted-4 (asc) lists, keep lowest 4 sorted asc in a[]
__device__ __forceinline__ void merge44(float* a, const float* b) {
  float m0 = fminf(a[0], b[3]), m1 = fminf(a[1], b[2]);
  float m2 = fminf(a[2], b[1]), m3 = fminf(a[3], b[0]);
  cmpex(m0, m2); cmpex(m1, m3); cmpex(m0, m1); cmpex(m2, m3);
  a[0] = m0; a[1] = m1; a[2] = m2; a[3] = m3;
}

__device__ __forceinline__ unsigned long long mk_key(float d, int idx) {
  unsigned int f = __float_as_uint(d);
  f ^= (f >> 31) ? 0xFFFFFFFFu : 0x80000000u;
  return ((unsigned long long)f << 32) | (unsigned int)idx;
}

// ---------------------------------------------------------------- kernel 0: weight packing + pts4 + packed-pair SoA
__global__ __launch_bounds__(256) void transpose_w(
    const float* __restrict__ wq, const float* __restrict__ wk, const float* __restrict__ wv,
    const float* __restrict__ w1, const float* __restrict__ xyz,
    float* __restrict__ wTq, float* __restrict__ wTk, float* __restrict__ wTv,
    float* __restrict__ w1T, float* __restrict__ wPack, float4* __restrict__ pts4,
    float* __restrict__ pp) {
  int t = blockIdx.x * 256 + threadIdx.x;
  if (t < 64 * 262) {
    int o = t / 262, c = t - o * 262;
    wTq[c * 64 + o] = wq[t];
    wTk[c * 64 + o] = wk[t];
    wTv[c * 64 + o] = wv[t];
  }
  if (t < 128 * 64) {
    int r = t >> 6, c2 = t & 63;
    w1T[c2 * 128 + r] = w1[t];  // w1T[o][c]
  }
  if (t < 49152) {  // wPack float4-layout [half][ct16][mm3][ph2][o64] = {U_{2ph},T_{2ph},U_{2ph+1},T_{2ph+1}}
    int c  = t & 3;
    int o  = (t >> 2) & 63;
    int ph = (t >> 8) & 1;
    int t2 = t >> 9;         // (half*16+ct)*3 + mm
    int mm = t2 % 3;
    int t3 = t2 / 3;         // half*16+ct
    int ct = t3 & 15;
    int half = t3 >> 4;
    const float* wsrc = (mm == 0) ? wq : ((mm == 1) ? wk : wv);
    int isT = c & 1;
    int rr  = 2 * ph + (c >> 1);
    int col = (isT ? 134 : 6) + 4 * (half * 16 + ct) + rr;
    wPack[t] = wsrc[o * 262 + col];
  }
  if (t < 4 * NN) {  // pts4[b*4096+i] = (x,y,z,|x|^2); pp = pair-interleaved SoA with -2 baked in
    int bb = t >> 12, i = t & 4095;
    const float* xb = xyz + (size_t)bb * 3 * NN;
    float x = xb[i], y = xb[NN + i], z = xb[2 * NN + i];
    float w = x * x + y * y + z * z;
    pts4[t] = make_float4(x, y, z, w);
    float* pb = pp + ((size_t)bb * 2048 + (i >> 1)) * 8 + (i & 1);
    pb[0] = -2.0f * x; pb[2] = -2.0f * y; pb[4] = -2.0f * z; pb[6] = w;
  }
}

// ---------------------------------------------------------------- kernel 1: kNN halves
// round-2 structure; 4-op packed distance (-2 baked into pp, me.w as FMA seed);
// single atomic per candidate pair in the hit path.
__global__ __launch_bounds__(1024, 4) void knn_half(const float4* __restrict__ pts4,
                                                    const float* __restrict__ pp,
                                                    unsigned long long* __restrict__ keys_ws) {
  __shared__ float bufA[64 * 64];
  __shared__ float bufB[64 * 64];
  __shared__ unsigned long long hits[32 * 65];
  __shared__ int cnt[64];
  const int b  = blockIdx.x >> 7;
  const int g  = (blockIdx.x >> 1) & 63;
  const int h  = blockIdx.x & 1;
  const int n0 = g << 6;
  const int ql = threadIdx.x & 63;
  const int ch = __builtin_amdgcn_readfirstlane(threadIdx.x >> 6);
  if (threadIdx.x < 64) cnt[threadIdx.x] = 0;
  const int q = n0 + ql;
  const float4* pb4 = pts4 + ((size_t)b << 12);
  const float4 me = pb4[q];
  const f2 mex = {me.x, me.x}, mey = {me.y, me.y}, mez = {me.z, me.z}, mew = {me.w, me.w};
  const float* ppb = pp + ((size_t)b << 14);  // b * 2048 pairs * 8 floats
  const int m0 = (h << 11) + (ch << 7);
  // exactly one wave's 128-window contains this block's 64 queries:
  const bool ovl = (((h << 4) + ch) == (n0 >> 7));
  // ---- pass 1: top-4 per 128-candidate window, 4 independent tracker chains ----
  float t0[4], t1[4], t2[4], t3[4];
#pragma unroll
  for (int u = 0; u < 4; ++u) { t0[u] = 3.0e38f; t1[u] = 3.0e38f; t2[u] = 3.0e38f; t3[u] = 3.0e38f; }
#pragma unroll 2
  for (int mb = m0; mb < m0 + 128; mb += 8) {
    const f4* pg4 = reinterpret_cast<const f4*>(ppb + (size_t)mb * 4);
    f2 d2[4];
#pragma unroll
    for (int u = 0; u < 4; ++u) {
      f4 A = pg4[2 * u], B = pg4[2 * u + 1];
      f2 X = A.xy, Y = A.zw, Z = B.xy, W = B.zw;  // X,Y,Z pre-scaled by -2
      f2 t = X * mex + mew;
      t = Y * mey + t;
      t = Z * mez + t;
      d2[u] = t + W;
    }
    if (ovl) {
#pragma unroll
      for (int u = 0; u < 4; ++u) {
        d2[u].x = (mb + 2 * u     == q) ? 3.0e38f : d2[u].x;
        d2[u].y = (mb + 2 * u + 1 == q) ? 3.0e38f : d2[u].y;
      }
    }
#pragma unroll
    for (int u = 0; u < 4; ++u) {
      float* bd = (u == 0) ? t0 : (u == 1) ? t1 : (u == 2) ? t2 : t3;
      float dx = d2[u].x, dy = d2[u].y;
      bd[3] = __builtin_amdgcn_fmed3f(dx, bd[2], bd[3]);
      bd[2] = __builtin_amdgcn_fmed3f(dx, bd[1], bd[2]);
      bd[1] = __builtin_amdgcn_fmed3f(dx, bd[0], bd[1]);
      bd[0] = fminf(bd[0], dx);
      bd[3] = __builtin_amdgcn_fmed3f(dy, bd[2], bd[3]);
      bd[2] = __builtin_amdgcn_fmed3f(dy, bd[1], bd[2]);
      bd[1] = __builtin_amdgcn_fmed3f(dy, bd[0], bd[1]);
      bd[0] = fminf(bd[0], dy);
    }
  }
  // in-register merge of the 4 sorted-4 lists -> lowest-4 of the 128 window
  merge44(t0, t1); merge44(t2, t3); merge44(t0, t2);
  {
    const int r0 = (ch * 4) * 64 + ql;
    bufA[r0] = t0[0]; bufA[r0 + 64] = t0[1]; bufA[r0 + 128] = t0[2]; bufA[r0 + 192] = t0[3];
  }
  __syncthreads();
  // ---- tau merge tree: fixed-address bitonic networks ----
  if (ch < 8) {  // 8 merges of (4,4)->8
    const int base = 8 * ch;
    float s[8];
#pragma unroll
    for (int i = 0; i < 4; ++i) s[i] = bufA[(base + i) * 64 + ql];
#pragma unroll
    for (int i = 0; i < 4; ++i) s[4 + i] = bufA[(base + 7 - i) * 64 + ql];  // B reversed
    bitonic_merge<8>(s);
#pragma unroll
    for (int i = 0; i < 8; ++i) bufB[(base + i) * 64 + ql] = s[i];
  }
  __syncthreads();
  if (ch < 4) {  // 4 merges of (8,8)->16
    const int base = 16 * ch;
    float s[16];
#pragma unroll
    for (int i = 0; i < 8; ++i) s[i] = bufB[(base + i) * 64 + ql];
#pragma unroll
    for (int i = 0; i < 8; ++i) s[8 + i] = bufB[(base + 15 - i) * 64 + ql];
    bitonic_merge<16>(s);
#pragma unroll
    for (int i = 0; i < 16; ++i) bufA[(base + i) * 64 + ql] = s[i];
  }
  __syncthreads();
  if (ch < 2) {  // 2 merges of (16,16)->lowest-16 sorted
    const int base = 32 * ch;
    float l[16];
#pragma unroll
    for (int i = 0; i < 16; ++i)
      l[i] = fminf(bufA[(base + i) * 64 + ql], bufA[(base + 31 - i) * 64 + ql]);
    bitonic_merge<16>(l);
#pragma unroll
    for (int i = 0; i < 16; ++i) bufB[(16 * ch + i) * 64 + ql] = l[i];
  }
  __syncthreads();
  if (ch == 0) {  // final: tau = 16th smallest = max of pairwise lows
    float m[16];
#pragma unroll
    for (int i = 0; i < 16; ++i)
      m[i] = fminf(bufB[i * 64 + ql], bufB[(31 - i) * 64 + ql]);
    float t = m[0];
#pragma unroll
    for (int i = 1; i < 16; ++i) t = fmaxf(t, m[i]);
    bufA[15 * 64 + ql] = t;
  }
  __syncthreads();
  const float tau = bufA[15 * 64 + ql];
  // ---- pass 2: collect candidates <= tau (full rescan, single atomic per pair) ----
#pragma unroll 2
  for (int mb = m0; mb < m0 + 128; mb += 8) {
    const f4* pg4 = reinterpret_cast<const f4*>(ppb + (size_t)mb * 4);
#pragma unroll
    for (int u = 0; u < 4; ++u) {
      f4 A = pg4[2 * u], B = pg4[2 * u + 1];
      f2 X = A.xy, Y = A.zw, Z = B.xy, W = B.zw;
      f2 t = X * mex + mew;
      t = Y * mey + t;
      t = Z * mez + t;
      f2 d = t + W;
      const int i0 = mb + 2 * u;
      if (ovl) {
        d.x = (i0     == q) ? 3.0e38f : d.x;
        d.y = (i0 + 1 == q) ? 3.0e38f : d.y;
      }
      const bool hx = d.x <= tau, hy = d.y <= tau;
      if (hx || hy) {
        const int nh = (int)hx + (int)hy;
        int pos = atomicAdd(&cnt[ql], nh);
        unsigned long long kx = mk_key(d.x, i0), ky = mk_key(d.y, i0 + 1);
        if (pos < 32) hits[pos * 65 + ql] = hx ? kx : ky;
        if (nh == 2 && pos < 31) hits[(pos + 1) * 65 + ql] = ky;
      }
    }
  }
  __syncthreads();
  const int l5 = threadIdx.x & 31;
#pragma unroll
  for (int t = 0; t < 2; ++t) {
    const int qq = (t * 1024 + (int)threadIdx.x) >> 5;
    int nv = cnt[qq]; nv = nv > 32 ? 32 : nv;
    unsigned long long key = (l5 < nv) ? hits[l5 * 65 + qq] : ~0ULL;
#pragma unroll
    for (int k = 2; k <= 32; k <<= 1) {
#pragma unroll
      for (int jm = k >> 1; jm > 0; jm >>= 1) {
        unsigned long long o2 = __shfl_xor(key, jm, 32);
        bool asc = ((l5 & k) == 0);
        bool lower = ((l5 & jm) == 0);
        unsigned long long mn = key < o2 ? key : o2;
        unsigned long long mx = key < o2 ? o2 : key;
        key = (lower == asc) ? mn : mx;
      }
    }
    if (l5 < 16) {
      const size_t gq = (size_t)((b << 12) + n0 + qq);
      keys_ws[((size_t)h << 18) + gq * 16 + l5] = key;
    }
  }
}

// ---------------------------------------------------------------- kernel 2: projections (packed U/T accumulators)
__global__ __launch_bounds__(512) void proj_kernel(
    const float* __restrict__ feature, const float* __restrict__ xyz,
    const float* __restrict__ wTq, const float* __restrict__ wTk, const float* __restrict__ wTv,
    const float* __restrict__ wPack,
    const float* __restrict__ bq, const float* __restrict__ bk, const float* __restrict__ bv,
    float* __restrict__ uqA, float* __restrict__ cq,
    float2* __restrict__ ukv,
    float* __restrict__ ck, float* __restrict__ cv) {
  __shared__ float fl[64][132];        // 33.8 KB
  __shared__ float4 wl[16 * 3 * 2 * 64];   // 96 KB
  const int p0 = blockIdx.x << 6;
  const int b  = p0 >> 12;
  const int n0 = p0 & 4095;
  {
    const int i  = threadIdx.x & 63;
    const int c0 = threadIdx.x >> 6;
    const float* fb = feature + (size_t)b * CCH * NN + n0 + i;
    for (int cc = c0; cc < CCH; cc += 8) fl[i][cc] = fb[(size_t)cc * NN];
    if (threadIdx.x < 192) {
      const int d = threadIdx.x >> 6;
      fl[i][128 + d] = xyz[((size_t)b * 3 + d) * NN + n0 + i];
    }
  }
  const int o  = threadIdx.x & 63;
  const int pg = threadIdx.x >> 6;
  const float4* wp = reinterpret_cast<const float4*>(wPack);
  f2 acc[3][8];
#pragma unroll
  for (int mm = 0; mm < 3; ++mm)
#pragma unroll
    for (int s = 0; s < 8; ++s) acc[mm][s] = (f2){0.f, 0.f};

  for (int half = 0; half < 2; ++half) {
    __syncthreads();
    for (int d4 = threadIdx.x; d4 < 6144; d4 += 512)
      wl[d4] = wp[half * 6144 + d4];
    __syncthreads();
#pragma unroll 4
    for (int ct = 0; ct < 16; ++ct) {
      float4 wA[3], wB[3];
#pragma unroll
      for (int mm = 0; mm < 3; ++mm) {
        wA[mm] = wl[((ct * 3 + mm) * 2 + 0) * 64 + o];
        wB[mm] = wl[((ct * 3 + mm) * 2 + 1) * 64 + o];
      }
      const int cglob = half * 16 + ct;
#pragma unroll
      for (int s = 0; s < 8; ++s) {
        const float4 f4w = *reinterpret_cast<const float4*>(&fl[pg * 8 + s][4 * cglob]);
        const f2 sx = {f4w.x, f4w.x}, sy = {f4w.y, f4w.y}, sz = {f4w.z, f4w.z}, sw = {f4w.w, f4w.w};
#pragma unroll
        for (int mm = 0; mm < 3; ++mm) {
          const f2* a2 = reinterpret_cast<const f2*>(&wA[mm]);
          const f2* b2 = reinterpret_cast<const f2*>(&wB[mm]);
          f2 a = acc[mm][s];
          a += sx * a2[0];   // {U,T} += f.x * {U0,T0}
          a += sy * a2[1];
          a += sz * b2[0];
          a += sw * b2[1];
          acc[mm][s] = a;
        }
      }
    }
  }
  float wxu[3][3], wxt[3][3];
#pragma unroll
  for (int dd = 0; dd < 3; ++dd) {
    wxu[0][dd] = wTq[dd * 64 + o]; wxt[0][dd] = wTq[(3 + dd) * 64 + o];
    wxu[1][dd] = wTk[dd * 64 + o]; wxt[1][dd] = wTk[(3 + dd) * 64 + o];
    wxu[2][dd] = wTv[dd * 64 + o]; wxt[2][dd] = wTv[(3 + dd) * 64 + o];
  }
  const float bo0 = bq[o], bo1 = bk[o], bo2 = bv[o];
#pragma unroll
  for (int s = 0; s < 8; ++s) {
    const int p = pg * 8 + s;
    const float x = fl[p][128], y = fl[p][129], z = fl[p][130];
    const size_t gp = ((size_t)(p0 + p)) * 64 + o;
    float uu, tt;
    uu = acc[0][s].x + wxu[0][0] * x + wxu[0][1] * y + wxu[0][2] * z;
    tt = acc[0][s].y + wxt[0][0] * x + wxt[0][1] * y + wxt[0][2] * z;
    uqA[gp] = uu; cq[gp] = tt + bo0 - uu;
    const float uk_ = acc[1][s].x + wxu[1][0] * x + wxu[1][1] * y + wxu[1][2] * z;
    tt = acc[1][s].y + wxt[1][0] * x + wxt[1][1] * y + wxt[1][2] * z;
    ck[gp] = tt + bo1 - uk_;
    const float uv_ = acc[2][s].x + wxu[2][0] * x + wxu[2][1] * y + wxu[2][2] * z;
    tt = acc[2][s].y + wxt[2][0] * x + wxt[2][1] * y + wxt[2][2] * z;
    cv[gp] = tt + bo2 - uv_;
    ukv[gp] = make_float2(uk_, uv_);
  }
}

// ---------------------------------------------------------------- kernel 3: attention core + inline half-merge
__global__ __launch_bounds__(256) void attn_core(
    const unsigned long long* __restrict__ keys_ws,
    const float* __restrict__ uqA, const float* __restrict__ cq,
    const float2* __restrict__ ukv,
    const float* __restrict__ ck, const float* __restrict__ cv,
    float* __restrict__ res_ws) {
  __shared__ float kq[4][24][68];
  const int slot = threadIdx.x >> 6;
  const int o    = threadIdx.x & 63;
  const int p = (blockIdx.x << 2) + slot;
  const int b = p >> 12;
  const int l5 = o & 31;
  unsigned long long key =
      (l5 < 16) ? keys_ws[(size_t)p * 16 + l5]
                : keys_ws[((size_t)1 << 18) + (size_t)p * 16 + (31 - l5)];  // B reversed
#pragma unroll
  for (int jm = 16; jm > 0; jm >>= 1) {
    unsigned long long o2 = __shfl_xor(key, jm, 32);
    bool lower = ((l5 & jm) == 0);
    unsigned long long mn = key < o2 ? key : o2;
    unsigned long long mx = key < o2 ? o2 : key;
    key = lower ? mn : mx;
  }
  const int kidx = (int)(key & 0xFFFFFFFFu);
  const size_t pb = (size_t)p * 64 + o;
  const float cqo = cq[pb], cko = ck[pb], cvo = cv[pb];
  const int rowbase = (b << 12) * 64;
  float v[16];
#pragma unroll
  for (int j = 0; j < 16; ++j) {
    int nb = __shfl(kidx, j);
    int row = rowbase + nb * 64 + o;
    float2 kv = ukv[row];
    kq[slot][j][o] = kv.x + cko;
    v[j] = kv.y + cvo;
    if (j < 8) kq[slot][16 + j][o] = uqA[row] + cqo;
  }
  const int i  = o >> 3;
  const int jj = o & 7;
  const float* qrow = &kq[slot][16 + i][0];
  const float* k0r  = &kq[slot][jj][0];
  const float* k1r  = &kq[slot][8 + jj][0];
  float s0 = 0.f, s1 = 0.f;
#pragma unroll
  for (int t = 0; t < 16; ++t) {
    float4 q4 = *reinterpret_cast<const float4*>(qrow + 4 * t);
    float4 a4 = *reinterpret_cast<const float4*>(k0r + 4 * t);
    float4 c4 = *reinterpret_cast<const float4*>(k1r + 4 * t);
    s0 += q4.x * a4.x + q4.y * a4.y + q4.z * a4.z + q4.w * a4.w;
    s1 += q4.x * c4.x + q4.y * c4.y + q4.z * c4.z + q4.w * c4.w;
  }
  float mx = fmaxf(s0, s1);
  mx = fmaxf(mx, __shfl_xor(mx, 1));
  mx = fmaxf(mx, __shfl_xor(mx, 2));
  mx = fmaxf(mx, __shfl_xor(mx, 4));
  float e0 = __expf(s0 - mx), e1 = __expf(s1 - mx);
  float den = e0 + e1;
  den += __shfl_xor(den, 1);
  den += __shfl_xor(den, 2);
  den += __shfl_xor(den, 4);
  const float inv = 1.0f / den;
  float w0 = e0 * inv, w1s = e1 * inv;
  w0 += __shfl_xor(w0, 8);   w1s += __shfl_xor(w1s, 8);
  w0 += __shfl_xor(w0, 16);  w1s += __shfl_xor(w1s, 16);
  w0 += __shfl_xor(w0, 32);  w1s += __shfl_xor(w1s, 32);
  float res = 0.f;
#pragma unroll
  for (int j = 0; j < 8; ++j) {
    res += __shfl(w0, j)  * v[j];
    res += __shfl(w1s, j) * v[j + 8];
  }
  res_ws[pb] = res;
}

// ---------------------------------------------------------------- kernel 4: output epilogue
__global__ __launch_bounds__(512) void out_kernel(
    const float* __restrict__ feature, const float* __restrict__ res,
    const float* __restrict__ w1T, const float* __restrict__ b1,
    float* __restrict__ out) {
  __shared__ float rT[64][66];
  const int p0 = blockIdx.x << 6;
  const int b  = p0 >> 12;
  const int n0 = p0 & 4095;
  {
    const int o = threadIdx.x & 63;
    for (int pp = threadIdx.x >> 6; pp < 64; pp += 8)
      rT[o][pp] = res[(size_t)(p0 + pp) * 64 + o];
  }
  __syncthreads();
  const int n = threadIdx.x & 63;
  const int c0 = (threadIdx.x >> 6) * 16;
  float acc[16];
#pragma unroll
  for (int cc = 0; cc < 16; ++cc) acc[cc] = b1[c0 + cc];
  for (int o = 0; o < 64; ++o) {
    const float rr = rT[o][n];
    const float* wrow = &w1T[o * 128 + c0];
#pragma unroll
    for (int cc = 0; cc < 16; ++cc) acc[cc] += wrow[cc] * rr;
  }
#pragma unroll
  for (int cc = 0; cc < 16; ++cc) {
    const size_t gi = ((size_t)(b * 128 + c0 + cc) << 12) + n0 + n;
    out[gi] = acc[cc] + feature[gi];
  }
}

// ---------------------------------------------------------------- launch
extern "C" void kernel_launch(void* const* d_in, const int* in_sizes, int n_in,
                              void* d_out, int out_size, void* d_ws, size_t ws_size,
                              hipStream_t stream) {
  const float* feature = (const float*)d_in[0];
  const float* xyz     = (const float*)d_in[1];
  const float* wq      = (const float*)d_in[2];
  const float* bq      = (const float*)d_in[3];
  const float* wk      = (const float*)d_in[4];
  const float* bk      = (const float*)d_in[5];
  const float* wv      = (const float*)d_in[6];
  const float* bv      = (const float*)d_in[7];
  const float* w1      = (const float*)d_in[8];
  const float* b1      = (const float*)d_in[9];
  float* out = (float*)d_out;

  char* ws = (char*)d_ws;
  float4* pts4 = (float4*)(ws + (1u << 20));        // 256 KB
  float*  pp   = (float*)(ws + (1u << 20) + 262144); // 256 KB packed-pair SoA
  float*  uqA  = (float*)(ws + (2u << 20));         // 4 MB
  float*  cq   = (float*)(ws + (6u << 20));         // 4 MB
  float*  ck   = (float*)(ws + (10u << 20));        // 4 MB
  float*  cv   = (float*)(ws + (14u << 20));        // 4 MB
  float2* ukv  = (float2*)(ws + (18u << 20));       // 8 MB
  float*  res  = (float*)(ws + (26u << 20));        // 4 MB
  float*  wTq  = (float*)(ws + (30u << 20));
  float*  wTk  = wTq + 262 * 64;
  float*  wTv  = wTk + 262 * 64;
  float*  w1T  = wTv + 262 * 64;
  float*  wPk  = w1T + 128 * 64;                    // 49152 floats
  unsigned long long* keys = (unsigned long long*)(ws + (31u << 20));  // 4 MB

  transpose_w<<<192, 256, 0, stream>>>(wq, wk, wv, w1, xyz, wTq, wTk, wTv, w1T, wPk, pts4, pp);
  knn_half<<<512, 1024, 0, stream>>>(pts4, pp, keys);
  proj_kernel<<<256, 512, 0, stream>>>(feature, xyz, wTq, wTk, wTv, wPk, bq, bk, bv,
                                       uqA, cq, ukv, ck, cv);
  attn_core<<<4096, 256, 0, stream>>>(keys, uqA, cq, ukv, ck, cv, res);
  out_kernel<<<256, 512, 0, stream>>>(feature, res, w1T, b1, out);
}

// Round 5
// 194.222 us; speedup vs baseline: 1.1396x; 1.0134x over previous
//
#include <hip/hip_runtime.h>

#define NN 4096
#define CCH 128

typedef float f2 __attribute__((ext_vector_type(2)));
typedef float f4 __attribute__((ext_vector_type(4)));

__device__ __forceinline__ void cmpex(float& x, float& y) {
  float mn = fminf(x, y);
  y = fmaxf(x, y);
  x = mn;
}

template <int N>
__device__ __forceinline__ void bitonic_merge(float* s) {
#pragma unroll
  for (int jm = N / 2; jm > 0; jm >>= 1)
#pragma unroll
    for (int i = 0; i < N; ++i)
      if ((i & jm) == 0) cmpex(s[i], s[i + jm]);
}

// merge two sorted-4 (asc) lists, keep lowest 4 sorted asc in a[]
__device__ __forceinline__ void merge44(float* a, const float* b) {
  float m0 = fminf(a[0], b[3]), m1 = fminf(a[1], b[2]);
  float m2 = fminf(a[2], b[1]), m3 = fminf(a[3], b[0]);
  cmpex(m0, m2); cmpex(m1, m3); cmpex(m0, m1); cmpex(m2, m3);
  a[0] = m0; a[1] = m1; a[2] = m2; a[3] = m3;
}

// ---------------------------------------------------------------- kernel 0: weight packing + pts4 + packed-pair SoA
__global__ __launch_bounds__(256) void transpose_w(
    const float* __restrict__ wq, const float* __restrict__ wk, const float* __restrict__ wv,
    const float* __restrict__ w1, const float* __restrict__ xyz,
    float* __restrict__ wTq, float* __restrict__ wTk, float* __restrict__ wTv,
    float* __restrict__ w1T, float* __restrict__ wPack, float4* __restrict__ pts4,
    float* __restrict__ pp) {
  int t = blockIdx.x * 256 + threadIdx.x;
  if (t < 64 * 262) {
    int o = t / 262, c = t - o * 262;
    wTq[c * 64 + o] = wq[t];
    wTk[c * 64 + o] = wk[t];
    wTv[c * 64 + o] = wv[t];
  }
  if (t < 128 * 64) {
    int r = t >> 6, c2 = t & 63;
    w1T[c2 * 128 + r] = w1[t];  // w1T[o][c]
  }
  if (t < 49152) {  // wPack float4-layout [half][ct16][mm3][ph2][o64] = {U_{2ph},T_{2ph},U_{2ph+1},T_{2ph+1}}
    int c  = t & 3;
    int o  = (t >> 2) & 63;
    int ph = (t >> 8) & 1;
    int t2 = t >> 9;         // (half*16+ct)*3 + mm
    int mm = t2 % 3;
    int t3 = t2 / 3;         // half*16+ct
    int ct = t3 & 15;
    int half = t3 >> 4;
    const float* wsrc = (mm == 0) ? wq : ((mm == 1) ? wk : wv);
    int isT = c & 1;
    int rr  = 2 * ph + (c >> 1);
    int col = (isT ? 134 : 6) + 4 * (half * 16 + ct) + rr;
    wPack[t] = wsrc[o * 262 + col];
  }
  if (t < 4 * NN) {  // pts4[b*4096+i] = (x,y,z,|x|^2); pp = pair-interleaved SoA
    int bb = t >> 12, i = t & 4095;
    const float* xb = xyz + (size_t)bb * 3 * NN;
    float x = xb[i], y = xb[NN + i], z = xb[2 * NN + i];
    float w = x * x + y * y + z * z;
    pts4[t] = make_float4(x, y, z, w);
    float* pb = pp + ((size_t)bb * 2048 + (i >> 1)) * 8 + (i & 1);
    pb[0] = x; pb[2] = y; pb[4] = z; pb[6] = w;
  }
}

// ---------------------------------------------------------------- kernel 1: kNN halves (round-2 exact)
__global__ __launch_bounds__(1024, 4) void knn_half(const float4* __restrict__ pts4,
                                                    const float* __restrict__ pp,
                                                    unsigned long long* __restrict__ keys_ws) {
  __shared__ float bufA[64 * 64];
  __shared__ float bufB[64 * 64];
  __shared__ unsigned long long hits[32 * 65];
  __shared__ int cnt[64];
  const int b  = blockIdx.x >> 7;
  const int g  = (blockIdx.x >> 1) & 63;
  const int h  = blockIdx.x & 1;
  const int n0 = g << 6;
  const int ql = threadIdx.x & 63;
  const int ch = __builtin_amdgcn_readfirstlane(threadIdx.x >> 6);
  if (threadIdx.x < 64) cnt[threadIdx.x] = 0;
  const int q = n0 + ql;
  const float4* pb4 = pts4 + ((size_t)b << 12);
  const float4 me = pb4[q];
  const f2 mex = {me.x, me.x}, mey = {me.y, me.y}, mez = {me.z, me.z}, mew = {me.w, me.w};
  const f2 mneg2 = {-2.0f, -2.0f};
  const float* ppb = pp + ((size_t)b << 14);  // b * 2048 pairs * 8 floats
  const int m0 = (h << 11) + (ch << 7);
  // exactly one wave's 128-window contains this block's 64 queries:
  const bool ovl = (((h << 4) + ch) == (n0 >> 7));
  // ---- pass 1: top-4 per 128-candidate window, 4 independent tracker chains ----
  float t0[4], t1[4], t2[4], t3[4];
#pragma unroll
  for (int u = 0; u < 4; ++u) { t0[u] = 3.0e38f; t1[u] = 3.0e38f; t2[u] = 3.0e38f; t3[u] = 3.0e38f; }
#pragma unroll 2
  for (int mb = m0; mb < m0 + 128; mb += 8) {
    const f4* pg4 = reinterpret_cast<const f4*>(ppb + (size_t)mb * 4);
    f2 d2[4];
#pragma unroll
    for (int u = 0; u < 4; ++u) {
      f4 A = pg4[2 * u], B = pg4[2 * u + 1];
      f2 X = A.xy, Y = A.zw, Z = B.xy, W = B.zw;
      f2 dot = X * mex + Y * mey + Z * mez;
      d2[u] = dot * mneg2 + (W + mew);
    }
    if (ovl) {
#pragma unroll
      for (int u = 0; u < 4; ++u) {
        d2[u].x = (mb + 2 * u     == q) ? 3.0e38f : d2[u].x;
        d2[u].y = (mb + 2 * u + 1 == q) ? 3.0e38f : d2[u].y;
      }
    }
#pragma unroll
    for (int u = 0; u < 4; ++u) {
      float* bd = (u == 0) ? t0 : (u == 1) ? t1 : (u == 2) ? t2 : t3;
      float dx = d2[u].x, dy = d2[u].y;
      bd[3] = __builtin_amdgcn_fmed3f(dx, bd[2], bd[3]);
      bd[2] = __builtin_amdgcn_fmed3f(dx, bd[1], bd[2]);
      bd[1] = __builtin_amdgcn_fmed3f(dx, bd[0], bd[1]);
      bd[0] = fminf(bd[0], dx);
      bd[3] = __builtin_amdgcn_fmed3f(dy, bd[2], bd[3]);
      bd[2] = __builtin_amdgcn_fmed3f(dy, bd[1], bd[2]);
      bd[1] = __builtin_amdgcn_fmed3f(dy, bd[0], bd[1]);
      bd[0] = fminf(bd[0], dy);
    }
  }
  // in-register merge of the 4 sorted-4 lists -> lowest-4 of the 128 window
  merge44(t0, t1); merge44(t2, t3); merge44(t0, t2);
  {
    const int r0 = (ch * 4) * 64 + ql;
    bufA[r0] = t0[0]; bufA[r0 + 64] = t0[1]; bufA[r0 + 128] = t0[2]; bufA[r0 + 192] = t0[3];
  }
  __syncthreads();
  // ---- tau merge tree: fixed-address bitonic networks ----
  if (ch < 8) {  // 8 merges of (4,4)->8
    const int base = 8 * ch;
    float s[8];
#pragma unroll
    for (int i = 0; i < 4; ++i) s[i] = bufA[(base + i) * 64 + ql];
#pragma unroll
    for (int i = 0; i < 4; ++i) s[4 + i] = bufA[(base + 7 - i) * 64 + ql];  // B reversed
    bitonic_merge<8>(s);
#pragma unroll
    for (int i = 0; i < 8; ++i) bufB[(base + i) * 64 + ql] = s[i];
  }
  __syncthreads();
  if (ch < 4) {  // 4 merges of (8,8)->16
    const int base = 16 * ch;
    float s[16];
#pragma unroll
    for (int i = 0; i < 8; ++i) s[i] = bufB[(base + i) * 64 + ql];
#pragma unroll
    for (int i = 0; i < 8; ++i) s[8 + i] = bufB[(base + 15 - i) * 64 + ql];
    bitonic_merge<16>(s);
#pragma unroll
    for (int i = 0; i < 16; ++i) bufA[(base + i) * 64 + ql] = s[i];
  }
  __syncthreads();
  if (ch < 2) {  // 2 merges of (16,16)->lowest-16 sorted
    const int base = 32 * ch;
    float l[16];
#pragma unroll
    for (int i = 0; i < 16; ++i)
      l[i] = fminf(bufA[(base + i) * 64 + ql], bufA[(base + 31 - i) * 64 + ql]);
    bitonic_merge<16>(l);
#pragma unroll
    for (int i = 0; i < 16; ++i) bufB[(16 * ch + i) * 64 + ql] = l[i];
  }
  __syncthreads();
  if (ch == 0) {  // final: tau = 16th smallest = max of pairwise lows
    float m[16];
#pragma unroll
    for (int i = 0; i < 16; ++i)
      m[i] = fminf(bufB[i * 64 + ql], bufB[(31 - i) * 64 + ql]);
    float t = m[0];
#pragma unroll
    for (int i = 1; i < 16; ++i) t = fmaxf(t, m[i]);
    bufA[15 * 64 + ql] = t;
  }
  __syncthreads();
  const float tau = bufA[15 * 64 + ql];
  // ---- pass 2: collect candidates <= tau ----
#pragma unroll 2
  for (int mb = m0; mb < m0 + 128; mb += 8) {
    const f4* pg4 = reinterpret_cast<const f4*>(ppb + (size_t)mb * 4);
#pragma unroll
    for (int u = 0; u < 4; ++u) {
      f4 A = pg4[2 * u], B = pg4[2 * u + 1];
      f2 X = A.xy, Y = A.zw, Z = B.xy, W = B.zw;
      f2 dot = X * mex + Y * mey + Z * mez;
      f2 d2 = dot * mneg2 + (W + mew);
      if (fminf(d2.x, d2.y) <= tau) {
        if (d2.x <= tau && (mb + 2 * u) != q) {
          int pos = atomicAdd(&cnt[ql], 1);
          if (pos < 32) {
            unsigned int f = __float_as_uint(d2.x);
            f ^= (f >> 31) ? 0xFFFFFFFFu : 0x80000000u;
            hits[pos * 65 + ql] = ((unsigned long long)f << 32) | (unsigned int)(mb + 2 * u);
          }
        }
        if (d2.y <= tau && (mb + 2 * u + 1) != q) {
          int pos = atomicAdd(&cnt[ql], 1);
          if (pos < 32) {
            unsigned int f = __float_as_uint(d2.y);
            f ^= (f >> 31) ? 0xFFFFFFFFu : 0x80000000u;
            hits[pos * 65 + ql] = ((unsigned long long)f << 32) | (unsigned int)(mb + 2 * u + 1);
          }
        }
      }
    }
  }
  __syncthreads();
  const int l5 = threadIdx.x & 31;
#pragma unroll
  for (int t = 0; t < 2; ++t) {
    const int qq = (t * 1024 + (int)threadIdx.x) >> 5;
    int nv = cnt[qq]; nv = nv > 32 ? 32 : nv;
    unsigned long long key = (l5 < nv) ? hits[l5 * 65 + qq] : ~0ULL;
#pragma unroll
    for (int k = 2; k <= 32; k <<= 1) {
#pragma unroll
      for (int jm = k >> 1; jm > 0; jm >>= 1) {
        unsigned long long o2 = __shfl_xor(key, jm, 32);
        bool asc = ((l5 & k) == 0);
        bool lower = ((l5 & jm) == 0);
        unsigned long long mn = key < o2 ? key : o2;
        unsigned long long mx = key < o2 ? o2 : key;
        key = (lower == asc) ? mn : mx;
      }
    }
    if (l5 < 16) {
      const size_t gq = (size_t)((b << 12) + n0 + qq);
      keys_ws[((size_t)h << 18) + gq * 16 + l5] = key;
    }
  }
}

// ---------------------------------------------------------------- kernel 2: projections
// packed U/T accumulators; quarter-staged weights (48 KB) + 32 KB feature tile = 80 KB LDS
// -> 2 blocks/CU. xyz for the epilogue comes from pts4 (bit-identical), not LDS.
__global__ __launch_bounds__(512) void proj_kernel(
    const float* __restrict__ feature, const float4* __restrict__ pts4,
    const float* __restrict__ wTq, const float* __restrict__ wTk, const float* __restrict__ wTv,
    const float* __restrict__ wPack,
    const float* __restrict__ bq, const float* __restrict__ bk, const float* __restrict__ bv,
    float* __restrict__ uqA, float* __restrict__ cq,
    float2* __restrict__ ukv,
    float* __restrict__ ck, float* __restrict__ cv) {
  __shared__ float fl[64][128];            // 32 KB (row stride 512 B, 16B-aligned)
  __shared__ float4 wl[8 * 3 * 2 * 64];    // 48 KB (one quarter of wPack)
  const int p0 = blockIdx.x << 6;
  const int b  = p0 >> 12;
  const int n0 = p0 & 4095;
  {
    const int i  = threadIdx.x & 63;
    const int c0 = threadIdx.x >> 6;
    const float* fb = feature + (size_t)b * CCH * NN + n0 + i;
    for (int cc = c0; cc < CCH; cc += 8) fl[i][cc] = fb[(size_t)cc * NN];
  }
  const int o  = threadIdx.x & 63;
  const int pg = threadIdx.x >> 6;
  const float4* wp = reinterpret_cast<const float4*>(wPack);
  f2 acc[3][8];
#pragma unroll
  for (int mm = 0; mm < 3; ++mm)
#pragma unroll
    for (int s = 0; s < 8; ++s) acc[mm][s] = (f2){0.f, 0.f};

  for (int qtr = 0; qtr < 4; ++qtr) {
    __syncthreads();
    for (int d4 = threadIdx.x; d4 < 3072; d4 += 512)
      wl[d4] = wp[qtr * 3072 + d4];
    __syncthreads();
#pragma unroll
    for (int ct = 0; ct < 8; ++ct) {
      float4 wA[3], wB[3];
#pragma unroll
      for (int mm = 0; mm < 3; ++mm) {
        wA[mm] = wl[((ct * 3 + mm) * 2 + 0) * 64 + o];
        wB[mm] = wl[((ct * 3 + mm) * 2 + 1) * 64 + o];
      }
      const int cglob = qtr * 8 + ct;
#pragma unroll
      for (int s = 0; s < 8; ++s) {
        const float4 f4w = *reinterpret_cast<const float4*>(&fl[pg * 8 + s][4 * cglob]);
        const f2 sx = {f4w.x, f4w.x}, sy = {f4w.y, f4w.y}, sz = {f4w.z, f4w.z}, sw = {f4w.w, f4w.w};
#pragma unroll
        for (int mm = 0; mm < 3; ++mm) {
          const f2* a2 = reinterpret_cast<const f2*>(&wA[mm]);
          const f2* b2 = reinterpret_cast<const f2*>(&wB[mm]);
          f2 a = acc[mm][s];
          a += sx * a2[0];   // {U,T} += f.x * {U0,T0}
          a += sy * a2[1];
          a += sz * b2[0];
          a += sw * b2[1];
          acc[mm][s] = a;
        }
      }
    }
  }
  float wxu[3][3], wxt[3][3];
#pragma unroll
  for (int dd = 0; dd < 3; ++dd) {
    wxu[0][dd] = wTq[dd * 64 + o]; wxt[0][dd] = wTq[(3 + dd) * 64 + o];
    wxu[1][dd] = wTk[dd * 64 + o]; wxt[1][dd] = wTk[(3 + dd) * 64 + o];
    wxu[2][dd] = wTv[dd * 64 + o]; wxt[2][dd] = wTv[(3 + dd) * 64 + o];
  }
  const float bo0 = bq[o], bo1 = bk[o], bo2 = bv[o];
  const float4* pt = pts4 + ((size_t)b << 12) + n0;
#pragma unroll
  for (int s = 0; s < 8; ++s) {
    const int p = pg * 8 + s;
    const float4 P = pt[p];
    const float x = P.x, y = P.y, z = P.z;
    const size_t gp = ((size_t)(p0 + p)) * 64 + o;
    float uu, tt;
    uu = acc[0][s].x + wxu[0][0] * x + wxu[0][1] * y + wxu[0][2] * z;
    tt = acc[0][s].y + wxt[0][0] * x + wxt[0][1] * y + wxt[0][2] * z;
    uqA[gp] = uu; cq[gp] = tt + bo0 - uu;
    const float uk_ = acc[1][s].x + wxu[1][0] * x + wxu[1][1] * y + wxu[1][2] * z;
    tt = acc[1][s].y + wxt[1][0] * x + wxt[1][1] * y + wxt[1][2] * z;
    ck[gp] = tt + bo1 - uk_;
    const float uv_ = acc[2][s].x + wxu[2][0] * x + wxu[2][1] * y + wxu[2][2] * z;
    tt = acc[2][s].y + wxt[2][0] * x + wxt[2][1] * y + wxt[2][2] * z;
    cv[gp] = tt + bo2 - uv_;
    ukv[gp] = make_float2(uk_, uv_);
  }
}

// ---------------------------------------------------------------- kernel 3: attention core + inline half-merge
__global__ __launch_bounds__(256) void attn_core(
    const unsigned long long* __restrict__ keys_ws,
    const float* __restrict__ uqA, const float* __restrict__ cq,
    const float2* __restrict__ ukv,
    const float* __restrict__ ck, const float* __restrict__ cv,
    float* __restrict__ res_ws) {
  __shared__ float kq[4][24][68];
  const int slot = threadIdx.x >> 6;
  const int o    = threadIdx.x & 63;
  const int p = (blockIdx.x << 2) + slot;
  const int b = p >> 12;
  const int l5 = o & 31;
  unsigned long long key =
      (l5 < 16) ? keys_ws[(size_t)p * 16 + l5]
                : keys_ws[((size_t)1 << 18) + (size_t)p * 16 + (31 - l5)];  // B reversed
#pragma unroll
  for (int jm = 16; jm > 0; jm >>= 1) {
    unsigned long long o2 = __shfl_xor(key, jm, 32);
    bool lower = ((l5 & jm) == 0);
    unsigned long long mn = key < o2 ? key : o2;
    unsigned long long mx = key < o2 ? o2 : key;
    key = lower ? mn : mx;
  }
  const int kidx = (int)(key & 0xFFFFFFFFu);
  const size_t pb = (size_t)p * 64 + o;
  const float cqo = cq[pb], cko = ck[pb], cvo = cv[pb];
  const int rowbase = (b << 12) * 64;
  float v[16];
#pragma unroll
  for (int j = 0; j < 16; ++j) {
    int nb = __shfl(kidx, j);
    int row = rowbase + nb * 64 + o;
    float2 kv = ukv[row];
    kq[slot][j][o] = kv.x + cko;
    v[j] = kv.y + cvo;
    if (j < 8) kq[slot][16 + j][o] = uqA[row] + cqo;
  }
  const int i  = o >> 3;
  const int jj = o & 7;
  const float* qrow = &kq[slot][16 + i][0];
  const float* k0r  = &kq[slot][jj][0];
  const float* k1r  = &kq[slot][8 + jj][0];
  float s0 = 0.f, s1 = 0.f;
#pragma unroll
  for (int t = 0; t < 16; ++t) {
    float4 q4 = *reinterpret_cast<const float4*>(qrow + 4 * t);
    float4 a4 = *reinterpret_cast<const float4*>(k0r + 4 * t);
    float4 c4 = *reinterpret_cast<const float4*>(k1r + 4 * t);
    s0 += q4.x * a4.x + q4.y * a4.y + q4.z * a4.z + q4.w * a4.w;
    s1 += q4.x * c4.x + q4.y * c4.y + q4.z * c4.z + q4.w * c4.w;
  }
  float mx = fmaxf(s0, s1);
  mx = fmaxf(mx, __shfl_xor(mx, 1));
  mx = fmaxf(mx, __shfl_xor(mx, 2));
  mx = fmaxf(mx, __shfl_xor(mx, 4));
  float e0 = __expf(s0 - mx), e1 = __expf(s1 - mx);
  float den = e0 + e1;
  den += __shfl_xor(den, 1);
  den += __shfl_xor(den, 2);
  den += __shfl_xor(den, 4);
  const float inv = 1.0f / den;
  float w0 = e0 * inv, w1s = e1 * inv;
  w0 += __shfl_xor(w0, 8);   w1s += __shfl_xor(w1s, 8);
  w0 += __shfl_xor(w0, 16);  w1s += __shfl_xor(w1s, 16);
  w0 += __shfl_xor(w0, 32);  w1s += __shfl_xor(w1s, 32);
  float res = 0.f;
#pragma unroll
  for (int j = 0; j < 8; ++j) {
    res += __shfl(w0, j)  * v[j];
    res += __shfl(w1s, j) * v[j + 8];
  }
  res_ws[pb] = res;
}

// ---------------------------------------------------------------- kernel 4: output epilogue
__global__ __launch_bounds__(512) void out_kernel(
    const float* __restrict__ feature, const float* __restrict__ res,
    const float* __restrict__ w1T, const float* __restrict__ b1,
    float* __restrict__ out) {
  __shared__ float rT[64][66];
  const int p0 = blockIdx.x << 6;
  const int b  = p0 >> 12;
  const int n0 = p0 & 4095;
  {
    const int o = threadIdx.x & 63;
    for (int pp = threadIdx.x >> 6; pp < 64; pp += 8)
      rT[o][pp] = res[(size_t)(p0 + pp) * 64 + o];
  }
  __syncthreads();
  const int n = threadIdx.x & 63;
  const int c0 = (threadIdx.x >> 6) * 16;
  float acc[16];
#pragma unroll
  for (int cc = 0; cc < 16; ++cc) acc[cc] = b1[c0 + cc];
  for (int o = 0; o < 64; ++o) {
    const float rr = rT[o][n];
    const float* wrow = &w1T[o * 128 + c0];
#pragma unroll
    for (int cc = 0; cc < 16; ++cc) acc[cc] += wrow[cc] * rr;
  }
#pragma unroll
  for (int cc = 0; cc < 16; ++cc) {
    const size_t gi = ((size_t)(b * 128 + c0 + cc) << 12) + n0 + n;
    out[gi] = acc[cc] + feature[gi];
  }
}

// ---------------------------------------------------------------- launch
extern "C" void kernel_launch(void* const* d_in, const int* in_sizes, int n_in,
                              void* d_out, int out_size, void* d_ws, size_t ws_size,
                              hipStream_t stream) {
  const float* feature = (const float*)d_in[0];
  const float* xyz     = (const float*)d_in[1];
  const float* wq      = (const float*)d_in[2];
  const float* bq      = (const float*)d_in[3];
  const float* wk      = (const float*)d_in[4];
  const float* bk      = (const float*)d_in[5];
  const float* wv      = (const float*)d_in[6];
  const float* bv      = (const float*)d_in[7];
  const float* w1      = (const float*)d_in[8];
  const float* b1      = (const float*)d_in[9];
  float* out = (float*)d_out;

  char* ws = (char*)d_ws;
  float4* pts4 = (float4*)(ws + (1u << 20));        // 256 KB
  float*  pp   = (float*)(ws + (1u << 20) + 262144); // 256 KB packed-pair SoA
  float*  uqA  = (float*)(ws + (2u << 20));         // 4 MB
  float*  cq   = (float*)(ws + (6u << 20));         // 4 MB
  float*  ck   = (float*)(ws + (10u << 20));        // 4 MB
  float*  cv   = (float*)(ws + (14u << 20));        // 4 MB
  float2* ukv  = (float2*)(ws + (18u << 20));       // 8 MB
  float*  res  = (float*)(ws + (26u << 20));        // 4 MB
  float*  wTq  = (float*)(ws + (30u << 20));
  float*  wTk  = wTq + 262 * 64;
  float*  wTv  = wTk + 262 * 64;
  float*  w1T  = wTv + 262 * 64;
  float*  wPk  = w1T + 128 * 64;                    // 49152 floats
  unsigned long long* keys = (unsigned long long*)(ws + (31u << 20));  // 4 MB

  transpose_w<<<192, 256, 0, stream>>>(wq, wk, wv, w1, xyz, wTq, wTk, wTv, w1T, wPk, pts4, pp);
  knn_half<<<512, 1024, 0, stream>>>(pts4, pp, keys);
  proj_kernel<<<256, 512, 0, stream>>>(feature, pts4, wTq, wTk, wTv, wPk, bq, bk, bv,
                                       uqA, cq, ukv, ck, cv);
  attn_core<<<4096, 256, 0, stream>>>(keys, uqA, cq, ukv, ck, cv, res);
  out_kernel<<<256, 512, 0, stream>>>(feature, res, w1T, b1, out);
}